// Round 8
// baseline (1220.159 us; speedup 1.0000x reference)
//
#include <hip/hip_runtime.h>

#define NI 8
#define NH 64
#define NO 8
#define NB 256
#define NT 2048
#define RING 16

// tanh(s) = 1 - 2/(exp(2s)+1); safe at +-inf
__device__ __forceinline__ float tanh_fast(float s) {
    float e = __expf(2.0f * s);
    return fmaf(-2.0f, __builtin_amdgcn_rcpf(e + 1.0f), 1.0f);
}

// broadcast lane k's value to all lanes via v_readlane (VALU, no LDS pipe)
__device__ __forceinline__ float rlane(float v, int k) {
    return __int_as_float(__builtin_amdgcn_readlane(__float_as_int(v), k));
}

// ---------------------------------------------------------------------------
// Clock-probe / DPM-boost ballast: saturates all 256 CUs (~130us @2.4GHz of
// pure dependent FMA). Purpose: test the hypothesis that the RNN's uniform
// ~3x slowdown vs instruction-count model is the chip running near idle
// clocks (~800MHz) for a 1-3%-utilization kernel. rocprof reports this
// kernel's dur separately from rnn_tri2's.
// ---------------------------------------------------------------------------
__global__ void __launch_bounds__(256) clock_ballast(float* ws) {
    float a = 0.5f + (float)threadIdx.x * 1e-6f;
    const float m = 1.0000001f, c = 0.9999999f;
    #pragma unroll 1
    for (int i = 0; i < 2500; ++i) {
        a = fmaf(a, m, c);  a = fmaf(a, m, -c);
        a = fmaf(a, m, c);  a = fmaf(a, m, -c);
        a = fmaf(a, m, c);  a = fmaf(a, m, -c);
        a = fmaf(a, m, c);  a = fmaf(a, m, -c);
    }
    // keep the chain live; d_ws is scratch, harmless if ever written
    if (a == 123.456789f && ws) ws[blockIdx.x & 7] = a;
}

// ---------------------------------------------------------------------------
// rnn_tri2: BYTE-IDENTICAL to round 7 (best so far, correctness-proven).
// Kept unchanged for a single-variable A/B on the clock hypothesis.
// ---------------------------------------------------------------------------
__global__ void __launch_bounds__(192, 1) rnn_tri2(
    const float* __restrict__ x,
    const float* __restrict__ W_ih0, const float* __restrict__ W_hh0,
    const float* __restrict__ b_ih0, const float* __restrict__ b_hh0,
    const float* __restrict__ W_ih1, const float* __restrict__ W_hh1,
    const float* __restrict__ b_ih1, const float* __restrict__ b_hh1,
    const float* __restrict__ W_fc,  const float* __restrict__ b_fc,
    float* __restrict__ out)
{
    const int b    = blockIdx.x;
    const int tid  = threadIdx.x;
    const int wid  = tid >> 6;
    const int lane = tid & 63;
    const int o    = lane & 7;
    const int kg   = lane >> 3;

    __shared__ float xs[2][64][NI];     // double-buffered x chunks (wave A)
    __shared__ float h0r[RING][NH];     // A -> B: h0[t] ring
    __shared__ float pir[RING][NH];     // B -> C: Wih1@h0[t] ring
    __shared__ float h1s[NH];           // C-local FC slice buffer
    __shared__ int   af, bfl, cfl;

    if (tid == 0) { af = -1; bfl = -1; cfl = -1; }

    // ---- single shared register arrays, role-selected source pointers ----
    float wrow[NH];
    const float* wsrc = (wid == 0) ? (W_hh0 + lane * NH)
                      : (wid == 1) ? (W_ih1 + lane * NH)
                                   : (W_hh1 + lane * NH);
    #pragma unroll
    for (int k = 0; k < NH; ++k) wrow[k] = wsrc[k];

    float wsm[8];
    const float* ssrc = (wid == 2) ? (W_fc + o * NH + kg * 8)
                                   : (W_ih0 + lane * NI);
    #pragma unroll
    for (int m = 0; m < 8; ++m) wsm[m] = ssrc[m];

    const float bias  = (wid == 0) ? (b_ih0[lane] + b_hh0[lane])
                      : (wid == 2) ? (b_ih1[lane] + b_hh1[lane]) : 0.0f;
    const float bias2 = (wid == 2) ? b_fc[o] : 0.0f;

    __syncthreads();                    // once, before the loop

    volatile int* vaf = &af;
    volatile int* vbf = &bfl;
    volatile int* vcf = &cfl;

    const float*  xb   = x   + (size_t)b * NT * NI;
    float*        outb = out + (size_t)b * NT * NO;
    const size_t  hid  = (size_t)NB * NT * NO;

    if (wid == 0) {
        // ================= wave A: layer-0 chain =================
        {
            float4 q0 = *(const float4*)(xb + (size_t)lane * NI);
            float4 q1 = *(const float4*)(xb + (size_t)lane * NI + 4);
            *(float4*)(&xs[0][lane][0]) = q0;
            *(float4*)(&xs[0][lane][4]) = q1;
        }
        float4 xn0 = {0,0,0,0}, xn1 = {0,0,0,0};
        float h0n = 0.0f;

        for (int t = 0; t < NT; ++t) {
            const int j = t & 63;
            if (j == 0) {                       // prefetch next chunk (global)
                const int c = (t >> 6) + 1;
                if (c < NT / 64) {
                    xn0 = *(const float4*)(xb + (size_t)(c * 64 + lane) * NI);
                    xn1 = *(const float4*)(xb + (size_t)(c * 64 + lane) * NI + 4);
                }
            }
            if ((t & 7) == 0) {                 // ring backpressure vs B
                while (*vbf < t - 9) __builtin_amdgcn_s_sleep(1);
                asm volatile("" ::: "memory");
            }
            const float4 xv0 = *(const float4*)(&xs[(t >> 6) & 1][j][0]);
            const float4 xv1 = *(const float4*)(&xs[(t >> 6) & 1][j][4]);

            float c0 = bias, c1 = 0.f, c2 = 0.f, c3 = 0.f;
            #pragma unroll
            for (int k = 0; k < NH; k += 8) {
                const float s0 = rlane(h0n, k + 0), s1 = rlane(h0n, k + 1);
                const float s2 = rlane(h0n, k + 2), s3 = rlane(h0n, k + 3);
                const float s4 = rlane(h0n, k + 4), s5 = rlane(h0n, k + 5);
                const float s6 = rlane(h0n, k + 6), s7 = rlane(h0n, k + 7);
                c0 = fmaf(s0, wrow[k + 0], c0); c1 = fmaf(s1, wrow[k + 1], c1);
                c2 = fmaf(s2, wrow[k + 2], c2); c3 = fmaf(s3, wrow[k + 3], c3);
                c0 = fmaf(s4, wrow[k + 4], c0); c1 = fmaf(s5, wrow[k + 5], c1);
                c2 = fmaf(s6, wrow[k + 6], c2); c3 = fmaf(s7, wrow[k + 7], c3);
            }
            c0 = fmaf(xv0.x, wsm[0], c0); c1 = fmaf(xv0.y, wsm[1], c1);
            c2 = fmaf(xv0.z, wsm[2], c2); c3 = fmaf(xv0.w, wsm[3], c3);
            c0 = fmaf(xv1.x, wsm[4], c0); c1 = fmaf(xv1.y, wsm[5], c1);
            c2 = fmaf(xv1.z, wsm[6], c2); c3 = fmaf(xv1.w, wsm[7], c3);
            h0n = tanh_fast((c0 + c1) + (c2 + c3));

            h0r[t & (RING - 1)][lane] = h0n;
            if (t & 1) {                        // publish gran 2
                asm volatile("s_waitcnt lgkmcnt(0)" ::: "memory");
                *vaf = t;
            }
            if (j == 48) {                      // LDS-write prefetched chunk
                const int c = (t >> 6) + 1;
                if (c < NT / 64) {
                    *(float4*)(&xs[c & 1][lane][0]) = xn0;
                    *(float4*)(&xs[c & 1][lane][4]) = xn1;
                }
            }
        }
        out[hid + (size_t)b * NH + lane] = h0n;                     // h0 final
    } else if (wid == 1) {
        // ================= wave B: pi producer =================
        for (int t = 0; t < NT; ++t) {
            if ((t & 3) == 0) {                 // availability from A (gran 4)
                const int need = (t + 3 < NT) ? t + 3 : NT - 1;
                while (*vaf < need) __builtin_amdgcn_s_sleep(1);
                asm volatile("" ::: "memory");
            }
            if ((t & 7) == 0) {                 // ring backpressure vs C
                while (*vcf < t - 9) __builtin_amdgcn_s_sleep(1);
                asm volatile("" ::: "memory");
            }
            float p0 = 0.f, p1 = 0.f, p2 = 0.f, p3 = 0.f;
            #pragma unroll
            for (int k = 0; k < NH; k += 4) {
                const float4 v = *(const float4*)(&h0r[t & (RING - 1)][k]);  // bcast
                p0 = fmaf(v.x, wrow[k + 0], p0);
                p1 = fmaf(v.y, wrow[k + 1], p1);
                p2 = fmaf(v.z, wrow[k + 2], p2);
                p3 = fmaf(v.w, wrow[k + 3], p3);
            }
            pir[t & (RING - 1)][lane] = (p0 + p1) + (p2 + p3);
            if (t & 1) {                        // publish gran 2
                asm volatile("s_waitcnt lgkmcnt(0)" ::: "memory");
                *vbf = t;
            }
        }
    } else {
        // ================= wave C: layer-1 chain + FC =================
        float h1p = 0.0f;

        for (int t = 0; t < NT; ++t) {
            if ((t & 3) == 0) {                 // availability from B (gran 4)
                const int need = (t + 3 < NT) ? t + 3 : NT - 1;
                while (*vbf < need) __builtin_amdgcn_s_sleep(1);
                asm volatile("" ::: "memory");
            }
            const float pv = pir[t & (RING - 1)][lane];

            float c0 = bias + pv, c1 = 0.f, c2 = 0.f, c3 = 0.f;
            #pragma unroll
            for (int k = 0; k < NH; k += 8) {
                const float s0 = rlane(h1p, k + 0), s1 = rlane(h1p, k + 1);
                const float s2 = rlane(h1p, k + 2), s3 = rlane(h1p, k + 3);
                const float s4 = rlane(h1p, k + 4), s5 = rlane(h1p, k + 5);
                const float s6 = rlane(h1p, k + 6), s7 = rlane(h1p, k + 7);
                c0 = fmaf(s0, wrow[k + 0], c0); c1 = fmaf(s1, wrow[k + 1], c1);
                c2 = fmaf(s2, wrow[k + 2], c2); c3 = fmaf(s3, wrow[k + 3], c3);
                c0 = fmaf(s4, wrow[k + 4], c0); c1 = fmaf(s5, wrow[k + 5], c1);
                c2 = fmaf(s6, wrow[k + 6], c2); c3 = fmaf(s7, wrow[k + 7], c3);
            }
            const float h1n = tanh_fast((c0 + c1) + (c2 + c3));

            h1s[lane] = h1n;
            const float4 u0 = *(const float4*)(&h1s[kg * 8]);
            const float4 u1 = *(const float4*)(&h1s[kg * 8 + 4]);
            float p = u0.x * wsm[0] + u0.y * wsm[1] + u0.z * wsm[2] + u0.w * wsm[3]
                    + u1.x * wsm[4] + u1.y * wsm[5] + u1.z * wsm[6] + u1.w * wsm[7];
            p += __shfl_xor(p, 8);
            p += __shfl_xor(p, 16);
            p += __shfl_xor(p, 32);
            if (lane < NO) outb[(size_t)t * NO + o] = p + bias2;  // fire-and-forget

            if ((t & 3) == 3) {                 // progress for B's backpressure
                asm volatile("s_waitcnt lgkmcnt(0)" ::: "memory");
                *vcf = t;
            }
            h1p = h1n;
        }
        out[hid + (size_t)NB * NH + (size_t)b * NH + lane] = h1p;   // h1 final
    }
}

extern "C" void kernel_launch(void* const* d_in, const int* in_sizes, int n_in,
                              void* d_out, int out_size, void* d_ws, size_t ws_size,
                              hipStream_t stream) {
    const float* x     = (const float*)d_in[0];
    const float* W_ih0 = (const float*)d_in[1];
    const float* W_hh0 = (const float*)d_in[2];
    const float* b_ih0 = (const float*)d_in[3];
    const float* b_hh0 = (const float*)d_in[4];
    const float* W_ih1 = (const float*)d_in[5];
    const float* W_hh1 = (const float*)d_in[6];
    const float* b_ih1 = (const float*)d_in[7];
    const float* b_hh1 = (const float*)d_in[8];
    const float* W_fc  = (const float*)d_in[9];
    const float* b_fc  = (const float*)d_in[10];

    // Clock probe / DPM boost: saturate all CUs briefly before the RNN.
    float* ws = (ws_size >= 32) ? (float*)d_ws : nullptr;
    clock_ballast<<<dim3(2048), dim3(256), 0, stream>>>(ws);

    rnn_tri2<<<dim3(NB), dim3(192), 0, stream>>>(
        x, W_ih0, W_hh0, b_ih0, b_hh0,
        W_ih1, W_hh1, b_ih1, b_hh1, W_fc, b_fc,
        (float*)d_out);
}

// Round 10
// 1008.631 us; speedup vs baseline: 1.2097x; 1.2097x over previous
//
#include <hip/hip_runtime.h>

#define NI 8
#define NH 64
#define NO 8
#define NB 256
#define NT 2048
#define RING 16

typedef float v2f __attribute__((ext_vector_type(2)));

// packed fp32 fma (v_pk_fma_f32 on CDNA): 2 FMAs per instruction
__device__ __forceinline__ v2f fma2(v2f a, v2f b, v2f c) {
    return __builtin_elementwise_fma(a, b, c);
}

// tanh(s) = 1 - 2/(exp(2s)+1); safe at +-inf
__device__ __forceinline__ float tanh_fast(float s) {
    float e = __expf(2.0f * s);
    return fmaf(-2.0f, __builtin_amdgcn_rcpf(e + 1.0f), 1.0f);
}

// R9 structure with the FC-bias bug fixed: bias2 is added AFTER the shfl_xor
// reduction (R9 folded it into each of the 8 partial lanes -> 7x bias error,
// absmax 0.816 == 7 * max|b_fc|).
//  1. amdgpu_waves_per_eu(1,1): truthful (1 block/CU, 3 waves on 4 SIMDs);
//     relaxes the allocator's VGPR budget (R8: 52 arch VGPRs for ~90 live).
//  2. dots via LDS b128 broadcast (16 reads) + v_pk_fma (32 ops) instead of
//     64 v_readlane + 64 scalar fma: ~49 vs ~130 instrs per 64-dot.
__attribute__((amdgpu_waves_per_eu(1, 1)))
__global__ void __launch_bounds__(192) rnn_pk2(
    const float* __restrict__ x,
    const float* __restrict__ W_ih0, const float* __restrict__ W_hh0,
    const float* __restrict__ b_ih0, const float* __restrict__ b_hh0,
    const float* __restrict__ W_ih1, const float* __restrict__ W_hh1,
    const float* __restrict__ b_ih1, const float* __restrict__ b_hh1,
    const float* __restrict__ W_fc,  const float* __restrict__ b_fc,
    float* __restrict__ out)
{
    const int b    = blockIdx.x;
    const int tid  = threadIdx.x;
    const int wid  = tid >> 6;
    const int lane = tid & 63;
    const int o    = lane & 7;
    const int kg   = lane >> 3;

    __shared__ float xs[2][64][NI];     // double-buffered x chunks (wave A)
    __shared__ float h0r[RING][NH];     // A -> B (and A self-gather) ring
    __shared__ float pir[RING][NH];     // B -> C ring
    __shared__ float h1s[NH];           // C self-gather + FC buffer
    __shared__ int   af, bfl, cfl;

    if (tid == 0) { af = -1; bfl = -1; cfl = -1; }

    // ---- packed per-lane weights, role-selected; pinned in VGPRs ----
    v2f w2[NH / 2];
    const float* wsrc = (wid == 0) ? (W_hh0 + lane * NH)
                      : (wid == 1) ? (W_ih1 + lane * NH)
                                   : (W_hh1 + lane * NH);
    #pragma unroll
    for (int k = 0; k < NH / 2; ++k) w2[k] = v2f{wsrc[2 * k], wsrc[2 * k + 1]};

    v2f wsm2[4];
    const float* ssrc = (wid == 2) ? (W_fc + o * NH + kg * 8)
                                   : (W_ih0 + lane * NI);
    #pragma unroll
    for (int m = 0; m < 4; ++m) wsm2[m] = v2f{ssrc[2 * m], ssrc[2 * m + 1]};

    #pragma unroll
    for (int k = 0; k < NH / 2; ++k) asm("" : "+v"(w2[k]));   // block remat/reload
    #pragma unroll
    for (int m = 0; m < 4; ++m) asm("" : "+v"(wsm2[m]));

    const float bias  = (wid == 0) ? (b_ih0[lane] + b_hh0[lane])
                      : (wid == 2) ? (b_ih1[lane] + b_hh1[lane]) : 0.0f;
    const float bias2 = (wid == 2) ? b_fc[o] : 0.0f;

    __syncthreads();                    // once, before the loop

    volatile int* vaf = &af;
    volatile int* vbf = &bfl;
    volatile int* vcf = &cfl;

    const float*  xb   = x   + (size_t)b * NT * NI;
    float*        outb = out + (size_t)b * NT * NO;
    const size_t  hid  = (size_t)NB * NT * NO;

    if (wid == 0) {
        // ================= wave A: layer-0 chain =================
        h0r[RING - 1][lane] = 0.0f;     // h0[-1] = 0 (gathered at t=0)
        {
            float4 q0 = *(const float4*)(xb + (size_t)lane * NI);
            float4 q1 = *(const float4*)(xb + (size_t)lane * NI + 4);
            *(float4*)(&xs[0][lane][0]) = q0;
            *(float4*)(&xs[0][lane][4]) = q1;
        }
        float4 xn0 = {0, 0, 0, 0}, xn1 = {0, 0, 0, 0};
        float h0n = 0.0f;

        for (int t = 0; t < NT; ++t) {
            const int j = t & 63;
            if (j == 0) {                       // prefetch next chunk (global)
                const int c = (t >> 6) + 1;
                if (c < NT / 64) {
                    xn0 = *(const float4*)(xb + (size_t)(c * 64 + lane) * NI);
                    xn1 = *(const float4*)(xb + (size_t)(c * 64 + lane) * NI + 4);
                }
            }
            if ((t & 7) == 0) {                 // ring backpressure vs B
                while (*vbf < t - 9) __builtin_amdgcn_s_sleep(1);
                asm volatile("" ::: "memory");
            }

            // gather h0[t-1] (broadcast b128) + x[t]; packed dual-fma dot
            const float4* hp = (const float4*)(&h0r[(t - 1) & (RING - 1)][0]);
            const float4* xp = (const float4*)(&xs[(t >> 6) & 1][j][0]);
            const float4 xg0 = xp[0], xg1 = xp[1];

            v2f a0 = {bias, 0.f}, a1 = {0.f, 0.f}, a2 = {0.f, 0.f}, a3 = {0.f, 0.f};
            #pragma unroll
            for (int k = 0; k < 16; ++k) {
                const float4 g = hp[k];
                const v2f lo = {g.x, g.y}, hi = {g.z, g.w};
                if (k & 1) { a2 = fma2(lo, w2[2 * k], a2); a3 = fma2(hi, w2[2 * k + 1], a3); }
                else       { a0 = fma2(lo, w2[2 * k], a0); a1 = fma2(hi, w2[2 * k + 1], a1); }
            }
            a0 = fma2(v2f{xg0.x, xg0.y}, wsm2[0], a0);
            a1 = fma2(v2f{xg0.z, xg0.w}, wsm2[1], a1);
            a2 = fma2(v2f{xg1.x, xg1.y}, wsm2[2], a2);
            a3 = fma2(v2f{xg1.z, xg1.w}, wsm2[3], a3);
            const v2f sv = (a0 + a1) + (a2 + a3);
            h0n = tanh_fast(sv.x + sv.y);

            h0r[t & (RING - 1)][lane] = h0n;
            if (t & 1) {                        // publish gran 2
                asm volatile("s_waitcnt lgkmcnt(0)" ::: "memory");
                *vaf = t;
            }
            if (j == 48) {                      // LDS-write prefetched chunk
                const int c = (t >> 6) + 1;
                if (c < NT / 64) {
                    *(float4*)(&xs[c & 1][lane][0]) = xn0;
                    *(float4*)(&xs[c & 1][lane][4]) = xn1;
                }
            }
        }
        out[hid + (size_t)b * NH + lane] = h0n;                     // h0 final
    } else if (wid == 1) {
        // ================= wave B: pi producer =================
        for (int t = 0; t < NT; ++t) {
            if ((t & 3) == 0) {                 // availability from A (gran 4)
                const int need = (t + 3 < NT) ? t + 3 : NT - 1;
                while (*vaf < need) __builtin_amdgcn_s_sleep(1);
                asm volatile("" ::: "memory");
            }
            if ((t & 7) == 0) {                 // ring backpressure vs C
                while (*vcf < t - 9) __builtin_amdgcn_s_sleep(1);
                asm volatile("" ::: "memory");
            }
            const float4* hp = (const float4*)(&h0r[t & (RING - 1)][0]);
            v2f a0 = {0.f, 0.f}, a1 = {0.f, 0.f}, a2 = {0.f, 0.f}, a3 = {0.f, 0.f};
            #pragma unroll
            for (int k = 0; k < 16; ++k) {
                const float4 g = hp[k];
                const v2f lo = {g.x, g.y}, hi = {g.z, g.w};
                if (k & 1) { a2 = fma2(lo, w2[2 * k], a2); a3 = fma2(hi, w2[2 * k + 1], a3); }
                else       { a0 = fma2(lo, w2[2 * k], a0); a1 = fma2(hi, w2[2 * k + 1], a1); }
            }
            const v2f sv = (a0 + a1) + (a2 + a3);
            pir[t & (RING - 1)][lane] = sv.x + sv.y;
            if (t & 1) {                        // publish gran 2
                asm volatile("s_waitcnt lgkmcnt(0)" ::: "memory");
                *vbf = t;
            }
        }
    } else {
        // ================= wave C: layer-1 chain + FC =================
        h1s[lane] = 0.0f;                       // h1[-1] = 0
        float h1n = 0.0f;

        for (int t = 0; t < NT; ++t) {
            if ((t & 3) == 0) {                 // availability from B (gran 4)
                const int need = (t + 3 < NT) ? t + 3 : NT - 1;
                while (*vbf < need) __builtin_amdgcn_s_sleep(1);
                asm volatile("" ::: "memory");
            }
            const float pv = pir[t & (RING - 1)][lane];   // issue early

            // gather h1[t-1] from h1s (written at end of prev iter; in-wave order)
            const float4* hp = (const float4*)(&h1s[0]);
            v2f a0 = {bias, 0.f}, a1 = {0.f, 0.f}, a2 = {0.f, 0.f}, a3 = {0.f, 0.f};
            #pragma unroll
            for (int k = 0; k < 16; ++k) {
                const float4 g = hp[k];
                const v2f lo = {g.x, g.y}, hi = {g.z, g.w};
                if (k & 1) { a2 = fma2(lo, w2[2 * k], a2); a3 = fma2(hi, w2[2 * k + 1], a3); }
                else       { a0 = fma2(lo, w2[2 * k], a0); a1 = fma2(hi, w2[2 * k + 1], a1); }
            }
            const v2f sv = (a0 + a1) + (a2 + a3);
            h1n = tanh_fast(sv.x + sv.y + pv);

            // write new h1 (in-order after the 16 reads above), then FC
            h1s[lane] = h1n;
            const float4 u0 = *(const float4*)(&h1s[kg * 8]);
            const float4 u1 = *(const float4*)(&h1s[kg * 8 + 4]);
            // NOTE: bias2 must NOT be in the pre-reduction accumulator
            v2f f0 = fma2(v2f{u0.x, u0.y}, wsm2[0], v2f{0.f, 0.f});
            v2f f1 = fma2(v2f{u0.z, u0.w}, wsm2[1], v2f{0.f, 0.f});
            f0 = fma2(v2f{u1.x, u1.y}, wsm2[2], f0);
            f1 = fma2(v2f{u1.z, u1.w}, wsm2[3], f1);
            const v2f fv = f0 + f1;
            float p = fv.x + fv.y;
            p += __shfl_xor(p, 8);
            p += __shfl_xor(p, 16);
            p += __shfl_xor(p, 32);
            if (lane < NO) outb[(size_t)t * NO + o] = p + bias2;   // bias AFTER reduce

            if ((t & 3) == 3) {                 // progress for B's backpressure
                asm volatile("s_waitcnt lgkmcnt(0)" ::: "memory");
                *vcf = t;
            }
        }
        out[hid + (size_t)NB * NH + (size_t)b * NH + lane] = h1n;   // h1 final
    }
}

extern "C" void kernel_launch(void* const* d_in, const int* in_sizes, int n_in,
                              void* d_out, int out_size, void* d_ws, size_t ws_size,
                              hipStream_t stream) {
    const float* x     = (const float*)d_in[0];
    const float* W_ih0 = (const float*)d_in[1];
    const float* W_hh0 = (const float*)d_in[2];
    const float* b_ih0 = (const float*)d_in[3];
    const float* b_hh0 = (const float*)d_in[4];
    const float* W_ih1 = (const float*)d_in[5];
    const float* W_hh1 = (const float*)d_in[6];
    const float* b_ih1 = (const float*)d_in[7];
    const float* b_hh1 = (const float*)d_in[8];
    const float* W_fc  = (const float*)d_in[9];
    const float* b_fc  = (const float*)d_in[10];

    rnn_pk2<<<dim3(NB), dim3(192), 0, stream>>>(
        x, W_ih0, W_hh0, b_ih0, b_hh0,
        W_ih1, W_hh1, b_ih1, b_hh1, W_fc, b_fc,
        (float*)d_out);
}